// Round 12
// baseline (532.496 us; speedup 1.0000x reference)
//
#include <hip/hip_runtime.h>
#include <cstdint>

#pragma clang fp contract(off)

typedef float    f32x4 __attribute__((ext_vector_type(4)));
typedef uint32_t u32x4 __attribute__((ext_vector_type(4)));

// ---------------------------------------------------------------------------
// threefry2x32, key (0,42), partitionable: counter (0,i), bits = x0 ^ x1.
// FROZEN semantics (validated PASS r9/r11). rotl now forced to v_alignbit_b32
// (1-inst rotate, bit-identical integer op).
// ---------------------------------------------------------------------------
__device__ __forceinline__ uint32_t rotl32(uint32_t x, uint32_t r) {
  return __builtin_amdgcn_alignbit(x, x, 32u - r);  // rotr(x, 32-r) == rotl(x, r)
}

__device__ __forceinline__ uint32_t threefry_bits(uint32_t idx) {
  const uint32_t ks0 = 0u;
  const uint32_t ks1 = 42u;
  const uint32_t ks2 = 0x1BD11BDAu ^ 0u ^ 42u;
  uint32_t x0 = 0u + ks0;
  uint32_t x1 = idx + ks1;
#define TF_R(r) { x0 += x1; x1 = rotl32(x1, r); x1 ^= x0; }
  TF_R(13u) TF_R(15u) TF_R(26u) TF_R(6u)
  x0 += ks1; x1 += ks2 + 1u;
  TF_R(17u) TF_R(29u) TF_R(16u) TF_R(24u)
  x0 += ks2; x1 += ks0 + 2u;
  TF_R(13u) TF_R(15u) TF_R(26u) TF_R(6u)
  x0 += ks0; x1 += ks1 + 3u;
  TF_R(17u) TF_R(29u) TF_R(16u) TF_R(24u)
  x0 += ks1; x1 += ks2 + 4u;
  TF_R(13u) TF_R(15u) TF_R(26u) TF_R(6u)
  x0 += ks2; x1 += ks0 + 5u;
#undef TF_R
  return x0 ^ x1;
}

// ---------------------------------------------------------------------------
// XLA Eigen no-FMA tanh, vectorized over 4 elems. Per-component rounding of
// v_pk_mul/add_f32 is identical to scalar v_mul/add → still bit-frozen.
// contract(off) file-wide keeps mul/add unfused.
// ---------------------------------------------------------------------------
__device__ __forceinline__ f32x4 xla_fast_tanh_v4(f32x4 x) {
  const f32x4 kC = (f32x4)7.90531110763549805f;
  f32x4 xc = __builtin_elementwise_min(__builtin_elementwise_max(x, -kC), kC);
  f32x4 x2 = xc * xc;
  f32x4 num = (f32x4)(-2.76076847742355e-16f);
  num = num * x2; num = num + 2.00018790482477e-13f;
  num = num * x2; num = num + -8.60467152213735e-11f;
  num = num * x2; num = num + 5.12229709037114e-08f;
  num = num * x2; num = num + 1.48572235717979e-05f;
  num = num * x2; num = num + 6.37261928875436e-04f;
  num = num * x2; num = num + 4.89352455891786e-03f;
  num = xc * num;
  f32x4 den = (f32x4)1.19825839466702e-06f;
  den = den * x2; den = den + 1.18534705686654e-04f;
  den = den * x2; den = den + 2.26843463243900e-03f;
  den = den * x2; den = den + 4.89352518554385e-03f;
  f32x4 r = num / den;                       // 4x IEEE div (frozen)
  f32x4 out;
#pragma unroll
  for (int j = 0; j < 4; ++j)
    out[j] = (fabsf(x[j]) < 0.0004f) ? x[j] : r[j];
  return out;
}

// ---------------------------------------------------------------------------
// Approx-tolerant tail: asin(side) = 2*atan(side/(1+sqrt(1-side^2))).
// contract(fast) scoped HERE only → pk_fma formation. Error additive ~1e-7.
// ---------------------------------------------------------------------------
__device__ __forceinline__ f32x4 asin_tail_v4(f32x4 side) {
#pragma clang fp contract(fast)
  f32x4 ss = side * side;
  f32x4 om = 1.0f - ss;
  f32x4 sq, s;
#pragma unroll
  for (int j = 0; j < 4; ++j) sq[j] = __builtin_amdgcn_sqrtf(om[j]);
  f32x4 d = 1.0f + sq;
#pragma unroll
  for (int j = 0; j < 4; ++j) s[j] = side[j] * __builtin_amdgcn_rcpf(d[j]);
  f32x4 t2 = s * s;
  f32x4 r = (f32x4)(-4.0540580e-3f);
  r = r * t2 + 2.18612288e-2f;
  r = r * t2 + -5.59098861e-2f;
  r = r * t2 + 9.64200441e-2f;
  r = r * t2 + -1.390853351e-1f;
  r = r * t2 + 1.994653599e-1f;
  r = r * t2 + -3.332985605e-1f;
  r = r * t2 + 9.999993329e-1f;
  return 4.0f * (s * r);
}

__global__ __launch_bounds__(256) void wmeasure_kernel(
    const f32x4* __restrict__ inp, const f32x4* __restrict__ ang,
    const f32x4* __restrict__ lres, float* __restrict__ out,
    int n4, int n) {
#pragma clang fp contract(off)
  const float kHalfPi = 1.5707963267948966f;
  const float kSinG   = 0.7071067811865476f;

  int i = blockIdx.x * blockDim.x + threadIdx.x;
  if (i >= n4) return;

  f32x4 vi = inp[i];
  f32x4 va = ang[i];
  f32x4 vl = lres[i];

  // ---- frozen meas chain (bit-identical to r9/r11 PASS) ----
  f32x4 t = xla_fast_tanh_v4(vi * 2.0f);
  f32x4 theta = kHalfPi * (vl - t);
  f32x4 temp = va + theta;
  f32x4 h = temp * 0.5f;
  f32x4 be, co;
#pragma unroll
  for (int j = 0; j < 4; ++j) {
    float sj, cj;
    sincosf(h[j], &sj, &cj);                 // ocml sincos == sinf/cosf (r11)
    be[j] = sj; co[j] = cj;
  }
  f32x4 exp_z = (co * co) - (be * be);
  f32x4 e = exp_z * kSinG;
  f32x4 onepe = 1.0f + e;
  f32x4 oneme = 1.0f - e;
  f32x4 p0 = __builtin_elementwise_max(onepe * 0.5f, (f32x4)0.0f);
  f32x4 p1 = __builtin_elementwise_max(oneme * 0.5f, (f32x4)0.0f);
  f32x4 ratio = p0 / (p0 + p1);              // IEEE div (frozen)

  u32x4 bits;
  uint32_t basei = ((uint32_t)i) << 2;
#pragma unroll
  for (int j = 0; j < 4; ++j) bits[j] = threefry_bits(basei + (uint32_t)j);
  u32x4 ub = (bits >> 9) | 0x3f800000u;
  f32x4 v = __builtin_bit_cast(f32x4, ub);
  f32x4 u = v - 1.0f;                        // exact (Sterbenz)

  f32x4 m, numr, denr;
#pragma unroll
  for (int j = 0; j < 4; ++j) {
    bool pos = u[j] < ratio[j];
    m[j]    = pos ? 1.0f : -1.0f;
    numr[j] = pos ? (1.0f - kSinG) : (1.0f + kSinG);  // const-folded, same fp
    denr[j] = pos ? onepe[j] : oneme[j];              // same fp as 1 + m*e
  }
  f32x4 q = numr / denr;                     // IEEE div (frozen)
  f32x4 sq;
#pragma unroll
  for (int j = 0; j < 4; ++j) sq[j] = sqrtf(q[j]);    // IEEE sqrt (frozen)
  f32x4 side = be * sq;
  side = __builtin_elementwise_min(
             __builtin_elementwise_max(side, (f32x4)(-1.0f)), (f32x4)1.0f);

  f32x4 nang = asin_tail_v4(side);

  reinterpret_cast<f32x4*>(out)[i] = m;            // meas_res   [0 .. n)
  reinterpret_cast<f32x4*>(out + n)[i] = nang;     // new_angles [n .. 2n)
}

extern "C" void kernel_launch(void* const* d_in, const int* in_sizes, int n_in,
                              void* d_out, int out_size, void* d_ws,
                              size_t ws_size, hipStream_t stream) {
  const f32x4* inp = (const f32x4*)d_in[0];
  const f32x4* ang = (const f32x4*)d_in[1];
  const f32x4* lr  = (const f32x4*)d_in[2];
  float* out = (float*)d_out;

  int n = in_sizes[0];
  int n4 = n >> 2;
  int blocks = (n4 + 255) / 256;

  wmeasure_kernel<<<blocks, 256, 0, stream>>>(inp, ang, lr, out, n4, n);
}